// Round 6
// baseline (626.978 us; speedup 1.0000x reference)
//
#include <hip/hip_runtime.h>
#include <hip/hip_bf16.h>
#include <stdint.h>

#define NNODES 50000
#define NEDGES 800000
#define LATENT 128
#define NTYPES 32
#define NTILES 12500   // NEDGES / 64
#define GRID_E 512     // 2 blocks/CU

typedef __bf16 bf16x8 __attribute__((ext_vector_type(8)));
typedef float floatx4 __attribute__((ext_vector_type(4)));
typedef unsigned int u32;

#if defined(__has_builtin)
#if __has_builtin(__builtin_amdgcn_global_load_lds)
#define HAS_GLD_LDS 1
#endif
#endif

// async 16B/lane gather into LDS. lbase must be wave-uniform; HW deposits at lbase + lane*16.
__device__ __forceinline__ void gather16(const __hip_bfloat16* g, __hip_bfloat16* lbase, int lane) {
#ifdef HAS_GLD_LDS
    __builtin_amdgcn_global_load_lds(
        (const __attribute__((address_space(1))) u32*)(uintptr_t)g,
        (__attribute__((address_space(3))) u32*)(u32)(uintptr_t)lbase,
        16, 0, 0);
#else
    *(uint4*)(lbase + lane * 8) = *(const uint4*)g;
#endif
}

__device__ __forceinline__ int load_idx(const int* ei, bool i64, int half, size_t e) {
    size_t pos = (size_t)half * NEDGES + e;
    return i64 ? ei[2 * pos] : ei[pos];
}

// ---------------- transpose+cast W1 -> W1T[256][256] bf16, W2 -> W2Tp[16][256] bf16 (rows 8..15 zero)
__global__ __launch_bounds__(256) void transpose_kernel(
    const float* __restrict__ W1, const float* __restrict__ W2,
    __hip_bfloat16* __restrict__ W1T, __hip_bfloat16* __restrict__ W2Tp) {
    int n = blockIdx.x;   // 0..255
    int k = threadIdx.x;  // 0..255
    W1T[n * 256 + k] = __float2bfloat16(W1[k * 256 + n]);
    if (n < 16) {
        __hip_bfloat16 v = __float2bfloat16(n < 8 ? W2[k * 8 + n] : 0.f);
        W2Tp[n * 256 + k] = v;
    }
}

// ---------------- node logits (fp32 vector) + fused z->bf16 cast
__global__ __launch_bounds__(256) void node_kernel(
    const float* __restrict__ z, const float* __restrict__ Wn,
    const float* __restrict__ bn, float* __restrict__ out,
    __hip_bfloat16* __restrict__ zbf) {
    __shared__ float wt[32][132];
    __shared__ float zl[8][128];
    int t = threadIdx.x;
#pragma unroll
    for (int i = 0; i < 16; ++i) {
        int flat = t + 256 * i;
        int k = flat >> 5, ty = flat & 31;
        wt[ty][k] = Wn[flat];
    }
    int node0 = blockIdx.x * 8;
    float4 v = ((const float4*)(z + (size_t)node0 * LATENT))[t];
    ((float4*)zl)[t] = v;
    {
        __hip_bfloat16 o[4];
        o[0] = __float2bfloat16(v.x); o[1] = __float2bfloat16(v.y);
        o[2] = __float2bfloat16(v.z); o[3] = __float2bfloat16(v.w);
        *(uint2*)&zbf[(size_t)node0 * LATENT + t * 4] = *(const uint2*)o;
    }
    __syncthreads();
    int ty = t & 31, ln = t >> 5;
    float acc = bn[ty];
#pragma unroll 16
    for (int k = 0; k < 128; ++k) acc += zl[ln][k] * wt[ty][k];
    out[(size_t)(node0 + ln) * NTYPES + ty] = acc;
}

// ---------------- fused edge MLP, 512-thread blocks, 2(M)x4(N) wave grid, multi-tile pipelined
// ef layout (per buffer): 64 rows x 32 chunks of 16B; chunk swizzle: phys = logical ^ (row & 7)
#define W2T_ROW 264

__global__ __launch_bounds__(512, 4) void edge_kernel(
    const __hip_bfloat16* __restrict__ zbf, const int* __restrict__ ei,
    const __hip_bfloat16* __restrict__ W1T, const float* __restrict__ b1,
    const __hip_bfloat16* __restrict__ W2T, const float* __restrict__ b2,
    float* __restrict__ out) {
    __shared__ __align__(16) __hip_bfloat16 ef[2][64 * 256];    // 2 x 32 KB
    __shared__ __align__(16) __hip_bfloat16 w2t[16 * W2T_ROW];  // 8448 B
    __shared__ int idx_lds[2][128];

    int t = threadIdx.x;
    int lane = t & 63, wave = t >> 6;        // 8 waves
    int l16 = lane & 15, quad = lane >> 4;
    int sw = l16 & 7;                        // LDS chunk swizzle for this lane
    int mi = wave >> 2;                      // 0..1  (M half)
    int ni = wave & 3;                       // 0..3  (N quarter)
    int nb = ni * 64;

    bool i64 = ((ei[1] | ei[3] | ei[5] | ei[7] | ei[9] | ei[11] | ei[13] | ei[15]) == 0);

    {   // stage W2T once: 512 threads cover 512 x 16B
        int n = t >> 5, c = t & 31;
        *(uint4*)&w2t[n * W2T_ROW + c * 8] = ((const uint4*)W2T)[t];
    }

    // B panel (N=64 x K=256 per wave) into registers: 32 x bf16x8 = 128 VGPRs
    bf16x8 breg[4][8];
#pragma unroll
    for (int nt = 0; nt < 4; ++nt) {
        const __hip_bfloat16* rowp = W1T + (size_t)(nb + nt * 16 + l16) * 256 + quad * 8;
#pragma unroll
        for (int kt = 0; kt < 8; ++kt) breg[nt][kt] = *(const bf16x8*)(rowp + kt * 32);
    }

    float b1v[4];
#pragma unroll
    for (int nt = 0; nt < 4; ++nt) b1v[nt] = b1[nb + nt * 16 + l16];
    float b2v = (l16 < 8) ? b2[l16] : 0.f;

    int tile = blockIdx.x;
    if (t < 128) idx_lds[0][t] = load_idx(ei, i64, t >> 6, (size_t)tile * 64 + (t & 63));
    __syncthreads();   // idx_lds[0] + w2t visible
    {   // issue DMA gather tile0 -> ef[0]: 8 waves x 4 issues x 64 lanes x 16B = 32 KB
#pragma unroll
        for (int i = 0; i < 4; ++i) {
            int s = (wave * 4 + i) * 64 + lane;
            int m = s >> 5, cp = s & 31;
            int c = cp ^ (m & 7);
            int node = idx_lds[0][(c >> 4) * 64 + m];
            gather16(zbf + (size_t)node * LATENT + (c & 15) * 8, &ef[0][(wave * 4 + i) * 512], lane);
        }
    }
    int v_idx = 0;
    {
        int t1 = tile + GRID_E; if (t1 >= NTILES) t1 = tile;
        if (t < 128) v_idx = load_idx(ei, i64, t >> 6, (size_t)t1 * 64 + (t & 63));
    }

    int cur = 0;
    for (; tile < NTILES; tile += GRID_E) {
        int nxt = cur ^ 1;
        if (t < 128) idx_lds[nxt][t] = v_idx;
        __syncthreads();   // drains DMA(cur); idx_lds[nxt] visible; prior layer-2 reads of ef[nxt] done

        {   // issue DMA gather (tile+G) -> ef[nxt]
#pragma unroll
            for (int i = 0; i < 4; ++i) {
                int s = (wave * 4 + i) * 64 + lane;
                int m = s >> 5, cp = s & 31;
                int c = cp ^ (m & 7);
                int node = idx_lds[nxt][(c >> 4) * 64 + m];
                gather16(zbf + (size_t)node * LATENT + (c & 15) * 8, &ef[nxt][(wave * 4 + i) * 512], lane);
            }
        }
        {   // prefetch idx(tile + 2G)
            int t2 = tile + 2 * GRID_E; if (t2 >= NTILES) t2 = tile;
            if (t < 128) v_idx = load_idx(ei, i64, t >> 6, (size_t)t2 * 64 + (t & 63));
        }

        // ---- layer 1 K-loop on ef[cur]; B from registers; wave does M=32 (2 m-tiles), N=64
        const __hip_bfloat16* efc = ef[cur];
        floatx4 acc[2][4];
#pragma unroll
        for (int a = 0; a < 2; ++a)
#pragma unroll
            for (int b = 0; b < 4; ++b) acc[a][b] = floatx4{0.f, 0.f, 0.f, 0.f};

#pragma unroll
        for (int kt = 0; kt < 8; ++kt) {
            bf16x8 afrag[2];
#pragma unroll
            for (int mtl = 0; mtl < 2; ++mtl) {
                int m = (mi * 2 + mtl) * 16 + l16;
                int chunk = m * 32 + ((kt * 4 + quad) ^ sw);
                afrag[mtl] = *(const bf16x8*)&efc[chunk * 8];
            }
#pragma unroll
            for (int mtl = 0; mtl < 2; ++mtl)
#pragma unroll
                for (int nt = 0; nt < 4; ++nt)
                    acc[mtl][nt] = __builtin_amdgcn_mfma_f32_16x16x32_bf16(
                        afrag[mtl], breg[nt][kt], acc[mtl][nt], 0, 0, 0);
        }

        __syncthreads();   // all A-reads of ef[cur] done

        // ---- ReLU + bias, H -> ef[cur] (swizzled layout)
        __hip_bfloat16* efh = ef[cur];
#pragma unroll
        for (int mtl = 0; mtl < 2; ++mtl)
#pragma unroll
            for (int nt = 0; nt < 4; ++nt)
#pragma unroll
                for (int r = 0; r < 4; ++r) {
                    float v = acc[mtl][nt][r] + b1v[nt];
                    v = v > 0.f ? v : 0.f;
                    int row = (mi * 2 + mtl) * 16 + quad * 4 + r;
                    int col = nb + nt * 16 + l16;
                    int ch = row * 32 + ((col >> 3) ^ (row & 7));
                    efh[ch * 8 + (col & 7)] = __float2bfloat16(v);
                }
        __syncthreads();   // H visible

        // ---- layer 2: waves 0..3 each take one m-tile of 16 edges; N=16 (cols 8..15 zero-padded)
        if (mi == 0) {
            floatx4 acc2 = floatx4{0.f, 0.f, 0.f, 0.f};
#pragma unroll
            for (int kt = 0; kt < 8; ++kt) {
                int m2 = ni * 16 + l16;
                int chunk = m2 * 32 + ((kt * 4 + quad) ^ sw);
                bf16x8 a2 = *(const bf16x8*)&efc[chunk * 8];
                bf16x8 b2f = *(const bf16x8*)&w2t[l16 * W2T_ROW + (kt * 4 + quad) * 8];
                acc2 = __builtin_amdgcn_mfma_f32_16x16x32_bf16(a2, b2f, acc2, 0, 0, 0);
            }
            if (l16 < 8) {
                size_t e0 = (size_t)tile * 64;
#pragma unroll
                for (int r = 0; r < 4; ++r) {
                    size_t erow = e0 + ni * 16 + quad * 4 + r;
                    out[erow * 8 + l16] = acc2[r] + b2v;
                }
            }
        }
        cur ^= 1;
    }
}

extern "C" void kernel_launch(void* const* d_in, const int* in_sizes, int n_in,
                              void* d_out, int out_size, void* d_ws, size_t ws_size,
                              hipStream_t stream) {
    const float* z  = (const float*)d_in[0];
    const int* ei   = (const int*)d_in[1];
    const float* Wn = (const float*)d_in[2];
    const float* bn = (const float*)d_in[3];
    const float* W1 = (const float*)d_in[4];
    const float* b1 = (const float*)d_in[5];
    const float* W2 = (const float*)d_in[6];
    const float* b2 = (const float*)d_in[7];
    float* out = (float*)d_out;

    __hip_bfloat16* zbf  = (__hip_bfloat16*)d_ws;            // 6,400,000 bf16
    __hip_bfloat16* W1T  = zbf + (size_t)NNODES * LATENT;    // 65,536 bf16
    __hip_bfloat16* W2Tp = W1T + 256 * 256;                  // 4,096 bf16

    hipLaunchKernelGGL(transpose_kernel, dim3(256), dim3(256), 0, stream, W1, W2, W1T, W2Tp);
    hipLaunchKernelGGL(node_kernel, dim3(NNODES / 8), dim3(256), 0, stream, z, Wn, bn, out, zbf);
    hipLaunchKernelGGL(edge_kernel, dim3(GRID_E), dim3(512), 0, stream,
                       zbf, ei, W1T, b1, W2Tp, b2, out + (size_t)NNODES * NTYPES);
}

// Round 7
// 259.052 us; speedup vs baseline: 2.4203x; 2.4203x over previous
//
#include <hip/hip_runtime.h>
#include <hip/hip_bf16.h>
#include <stdint.h>

#define NNODES 50000
#define NEDGES 800000
#define LATENT 128
#define NTYPES 32
#define NTILES 12500   // NEDGES / 64
#define GRID_E 512     // 2 blocks/CU

typedef __bf16 bf16x8 __attribute__((ext_vector_type(8)));
typedef float floatx4 __attribute__((ext_vector_type(4)));
typedef unsigned int u32;

#if defined(__has_builtin)
#if __has_builtin(__builtin_amdgcn_global_load_lds)
#define HAS_GLD_LDS 1
#endif
#endif

// async 16B/lane gather into LDS. lbase must be wave-uniform; HW deposits at lbase + lane*16.
__device__ __forceinline__ void gather16(const __hip_bfloat16* g, __hip_bfloat16* lbase, int lane) {
#ifdef HAS_GLD_LDS
    __builtin_amdgcn_global_load_lds(
        (const __attribute__((address_space(1))) u32*)(uintptr_t)g,
        (__attribute__((address_space(3))) u32*)(u32)(uintptr_t)lbase,
        16, 0, 0);
#else
    *(uint4*)(lbase + lane * 8) = *(const uint4*)g;
#endif
}

__device__ __forceinline__ int load_idx(const int* ei, bool i64, int half, size_t e) {
    size_t pos = (size_t)half * NEDGES + e;
    return i64 ? ei[2 * pos] : ei[pos];
}

// ---------------- transpose+cast W1 -> W1T[256][256] bf16, W2 -> W2Tp[16][256] bf16 (rows 8..15 zero)
__global__ __launch_bounds__(256) void transpose_kernel(
    const float* __restrict__ W1, const float* __restrict__ W2,
    __hip_bfloat16* __restrict__ W1T, __hip_bfloat16* __restrict__ W2Tp) {
    int n = blockIdx.x;   // 0..255
    int k = threadIdx.x;  // 0..255
    W1T[n * 256 + k] = __float2bfloat16(W1[k * 256 + n]);
    if (n < 16) {
        __hip_bfloat16 v = __float2bfloat16(n < 8 ? W2[k * 8 + n] : 0.f);
        W2Tp[n * 256 + k] = v;
    }
}

// ---------------- node logits (fp32 vector) + fused z->bf16 cast
__global__ __launch_bounds__(256) void node_kernel(
    const float* __restrict__ z, const float* __restrict__ Wn,
    const float* __restrict__ bn, float* __restrict__ out,
    __hip_bfloat16* __restrict__ zbf) {
    __shared__ float wt[32][132];
    __shared__ float zl[8][128];
    int t = threadIdx.x;
#pragma unroll
    for (int i = 0; i < 16; ++i) {
        int flat = t + 256 * i;
        int k = flat >> 5, ty = flat & 31;
        wt[ty][k] = Wn[flat];
    }
    int node0 = blockIdx.x * 8;
    float4 v = ((const float4*)(z + (size_t)node0 * LATENT))[t];
    ((float4*)zl)[t] = v;
    {
        __hip_bfloat16 o[4];
        o[0] = __float2bfloat16(v.x); o[1] = __float2bfloat16(v.y);
        o[2] = __float2bfloat16(v.z); o[3] = __float2bfloat16(v.w);
        *(uint2*)&zbf[(size_t)node0 * LATENT + t * 4] = *(const uint2*)o;
    }
    __syncthreads();
    int ty = t & 31, ln = t >> 5;
    float acc = bn[ty];
#pragma unroll 16
    for (int k = 0; k < 128; ++k) acc += zl[ln][k] * wt[ty][k];
    out[(size_t)(node0 + ln) * NTYPES + ty] = acc;
}

// ---------------- fused edge MLP, 512-thread blocks, 2(M)x4(N) wave grid, multi-tile pipelined
// ef layout (per buffer): 64 rows x 32 chunks of 16B; chunk swizzle: phys = logical ^ (row & 7)
// NOTE: __launch_bounds__ 2nd arg empirically acts as min BLOCKS/CU here:
//   (512,2) -> VGPR 128 (R5, no spill); (512,4) -> VGPR 64 (R6, breg spilled, FETCH 1.7 GB).
#define W2T_ROW 264

__global__ __launch_bounds__(512, 2) void edge_kernel(
    const __hip_bfloat16* __restrict__ zbf, const int* __restrict__ ei,
    const __hip_bfloat16* __restrict__ W1T, const float* __restrict__ b1,
    const __hip_bfloat16* __restrict__ W2T, const float* __restrict__ b2,
    float* __restrict__ out) {
    __shared__ __align__(16) __hip_bfloat16 ef[2][64 * 256];    // 2 x 32 KB
    __shared__ __align__(16) __hip_bfloat16 w2t[16 * W2T_ROW];  // 8448 B
    __shared__ int idx_lds[2][128];

    int t = threadIdx.x;
    int lane = t & 63, wave = t >> 6;        // 8 waves
    int l16 = lane & 15, quad = lane >> 4;
    int sw = l16 & 7;                        // LDS chunk swizzle for this lane
    int mi = wave >> 2;                      // 0..1  (M half)
    int ni = wave & 3;                       // 0..3  (N quarter)
    int nb = ni * 64;

    bool i64 = ((ei[1] | ei[3] | ei[5] | ei[7] | ei[9] | ei[11] | ei[13] | ei[15]) == 0);

    {   // stage W2T once: 512 threads cover 512 x 16B
        int n = t >> 5, c = t & 31;
        *(uint4*)&w2t[n * W2T_ROW + c * 8] = ((const uint4*)W2T)[t];
    }

    // B panel (N=64 x K=256 per wave) into registers: 32 x bf16x8 = 128 VGPRs
    bf16x8 breg[4][8];
#pragma unroll
    for (int nt = 0; nt < 4; ++nt) {
        const __hip_bfloat16* rowp = W1T + (size_t)(nb + nt * 16 + l16) * 256 + quad * 8;
#pragma unroll
        for (int kt = 0; kt < 8; ++kt) breg[nt][kt] = *(const bf16x8*)(rowp + kt * 32);
    }

    float b1v[4];
#pragma unroll
    for (int nt = 0; nt < 4; ++nt) b1v[nt] = b1[nb + nt * 16 + l16];
    float b2v = (l16 < 8) ? b2[l16] : 0.f;

    int tile = blockIdx.x;
    if (t < 128) idx_lds[0][t] = load_idx(ei, i64, t >> 6, (size_t)tile * 64 + (t & 63));
    __syncthreads();   // idx_lds[0] + w2t visible
    {   // issue DMA gather tile0 -> ef[0]: 8 waves x 4 issues x 64 lanes x 16B = 32 KB
#pragma unroll
        for (int i = 0; i < 4; ++i) {
            int s = (wave * 4 + i) * 64 + lane;
            int m = s >> 5, cp = s & 31;
            int c = cp ^ (m & 7);
            int node = idx_lds[0][(c >> 4) * 64 + m];
            gather16(zbf + (size_t)node * LATENT + (c & 15) * 8, &ef[0][(wave * 4 + i) * 512], lane);
        }
    }
    int v_idx = 0;
    {
        int t1 = tile + GRID_E; if (t1 >= NTILES) t1 = tile;
        if (t < 128) v_idx = load_idx(ei, i64, t >> 6, (size_t)t1 * 64 + (t & 63));
    }

    int cur = 0;
    for (; tile < NTILES; tile += GRID_E) {
        int nxt = cur ^ 1;
        if (t < 128) idx_lds[nxt][t] = v_idx;
        __syncthreads();   // drains DMA(cur); idx_lds[nxt] visible; prior layer-2 reads of ef[nxt] done

        {   // issue DMA gather (tile+G) -> ef[nxt]
#pragma unroll
            for (int i = 0; i < 4; ++i) {
                int s = (wave * 4 + i) * 64 + lane;
                int m = s >> 5, cp = s & 31;
                int c = cp ^ (m & 7);
                int node = idx_lds[nxt][(c >> 4) * 64 + m];
                gather16(zbf + (size_t)node * LATENT + (c & 15) * 8, &ef[nxt][(wave * 4 + i) * 512], lane);
            }
        }
        {   // prefetch idx(tile + 2G)
            int t2 = tile + 2 * GRID_E; if (t2 >= NTILES) t2 = tile;
            if (t < 128) v_idx = load_idx(ei, i64, t >> 6, (size_t)t2 * 64 + (t & 63));
        }

        // ---- layer 1 K-loop on ef[cur]; B from registers; wave does M=32 (2 m-tiles), N=64
        const __hip_bfloat16* efc = ef[cur];
        floatx4 acc[2][4];
#pragma unroll
        for (int a = 0; a < 2; ++a)
#pragma unroll
            for (int b = 0; b < 4; ++b) acc[a][b] = floatx4{0.f, 0.f, 0.f, 0.f};

#pragma unroll
        for (int kt = 0; kt < 8; ++kt) {
            bf16x8 afrag[2];
#pragma unroll
            for (int mtl = 0; mtl < 2; ++mtl) {
                int m = (mi * 2 + mtl) * 16 + l16;
                int chunk = m * 32 + ((kt * 4 + quad) ^ sw);
                afrag[mtl] = *(const bf16x8*)&efc[chunk * 8];
            }
#pragma unroll
            for (int mtl = 0; mtl < 2; ++mtl)
#pragma unroll
                for (int nt = 0; nt < 4; ++nt)
                    acc[mtl][nt] = __builtin_amdgcn_mfma_f32_16x16x32_bf16(
                        afrag[mtl], breg[nt][kt], acc[mtl][nt], 0, 0, 0);
        }

        __syncthreads();   // all A-reads of ef[cur] done

        // ---- ReLU + bias, H -> ef[cur] (swizzled layout)
        __hip_bfloat16* efh = ef[cur];
#pragma unroll
        for (int mtl = 0; mtl < 2; ++mtl)
#pragma unroll
            for (int nt = 0; nt < 4; ++nt)
#pragma unroll
                for (int r = 0; r < 4; ++r) {
                    float v = acc[mtl][nt][r] + b1v[nt];
                    v = v > 0.f ? v : 0.f;
                    int row = (mi * 2 + mtl) * 16 + quad * 4 + r;
                    int col = nb + nt * 16 + l16;
                    int ch = row * 32 + ((col >> 3) ^ (row & 7));
                    efh[ch * 8 + (col & 7)] = __float2bfloat16(v);
                }
        __syncthreads();   // H visible

        // ---- layer 2: waves 0..3 each take one m-tile of 16 edges; N=16 (cols 8..15 zero-padded)
        if (mi == 0) {
            floatx4 acc2 = floatx4{0.f, 0.f, 0.f, 0.f};
#pragma unroll
            for (int kt = 0; kt < 8; ++kt) {
                int m2 = ni * 16 + l16;
                int chunk = m2 * 32 + ((kt * 4 + quad) ^ sw);
                bf16x8 a2 = *(const bf16x8*)&efc[chunk * 8];
                bf16x8 b2f = *(const bf16x8*)&w2t[l16 * W2T_ROW + (kt * 4 + quad) * 8];
                acc2 = __builtin_amdgcn_mfma_f32_16x16x32_bf16(a2, b2f, acc2, 0, 0, 0);
            }
            if (l16 < 8) {
                size_t e0 = (size_t)tile * 64;
#pragma unroll
                for (int r = 0; r < 4; ++r) {
                    size_t erow = e0 + ni * 16 + quad * 4 + r;
                    out[erow * 8 + l16] = acc2[r] + b2v;
                }
            }
        }
        cur ^= 1;
    }
}

extern "C" void kernel_launch(void* const* d_in, const int* in_sizes, int n_in,
                              void* d_out, int out_size, void* d_ws, size_t ws_size,
                              hipStream_t stream) {
    const float* z  = (const float*)d_in[0];
    const int* ei   = (const int*)d_in[1];
    const float* Wn = (const float*)d_in[2];
    const float* bn = (const float*)d_in[3];
    const float* W1 = (const float*)d_in[4];
    const float* b1 = (const float*)d_in[5];
    const float* W2 = (const float*)d_in[6];
    const float* b2 = (const float*)d_in[7];
    float* out = (float*)d_out;

    __hip_bfloat16* zbf  = (__hip_bfloat16*)d_ws;            // 6,400,000 bf16
    __hip_bfloat16* W1T  = zbf + (size_t)NNODES * LATENT;    // 65,536 bf16
    __hip_bfloat16* W2Tp = W1T + 256 * 256;                  // 4,096 bf16

    hipLaunchKernelGGL(transpose_kernel, dim3(256), dim3(256), 0, stream, W1, W2, W1T, W2Tp);
    hipLaunchKernelGGL(node_kernel, dim3(NNODES / 8), dim3(256), 0, stream, z, Wn, bn, out, zbf);
    hipLaunchKernelGGL(edge_kernel, dim3(GRID_E), dim3(512), 0, stream,
                       zbf, ei, W1T, b1, W2Tp, b2, out + (size_t)NNODES * NTYPES);
}

// Round 8
// 251.658 us; speedup vs baseline: 2.4914x; 1.0294x over previous
//
#include <hip/hip_runtime.h>
#include <hip/hip_bf16.h>
#include <stdint.h>

#define NNODES 50000
#define NEDGES 800000
#define LATENT 128
#define NTYPES 32
#define NTILES 12500   // NEDGES / 64
#define GRID_E 256     // 1 block/CU (HW won't co-schedule 2: VGPR quantum > 128 at 512 thr)

typedef __bf16 bf16x8 __attribute__((ext_vector_type(8)));
typedef float floatx4 __attribute__((ext_vector_type(4)));
typedef unsigned int u32;

#if defined(__has_builtin)
#if __has_builtin(__builtin_amdgcn_global_load_lds)
#define HAS_GLD_LDS 1
#endif
#endif

// LDS-only barrier: waits lgkmcnt(0) but leaves vmcnt (async global_load_lds DMA) in flight.
// __syncthreads() would emit s_waitcnt vmcnt(0) and drain the next-tile gather — the R7 stall.
__device__ __forceinline__ void lds_barrier() {
    asm volatile("s_waitcnt lgkmcnt(0)\n\ts_barrier" ::: "memory");
}

// async 16B/lane gather into LDS. lbase must be wave-uniform; HW deposits at lbase + lane*16.
__device__ __forceinline__ void gather16(const __hip_bfloat16* g, __hip_bfloat16* lbase, int lane) {
#ifdef HAS_GLD_LDS
    __builtin_amdgcn_global_load_lds(
        (const __attribute__((address_space(1))) u32*)(uintptr_t)g,
        (__attribute__((address_space(3))) u32*)(u32)(uintptr_t)lbase,
        16, 0, 0);
#else
    *(uint4*)(lbase + lane * 8) = *(const uint4*)g;
#endif
}

__device__ __forceinline__ int load_idx(const int* ei, bool i64, int half, size_t e) {
    size_t pos = (size_t)half * NEDGES + e;
    return i64 ? ei[2 * pos] : ei[pos];
}

// ---------------- transpose+cast W1 -> W1T[256][256] bf16, W2 -> W2Tp[16][256] bf16 (rows 8..15 zero)
__global__ __launch_bounds__(256) void transpose_kernel(
    const float* __restrict__ W1, const float* __restrict__ W2,
    __hip_bfloat16* __restrict__ W1T, __hip_bfloat16* __restrict__ W2Tp) {
    int n = blockIdx.x;   // 0..255
    int k = threadIdx.x;  // 0..255
    W1T[n * 256 + k] = __float2bfloat16(W1[k * 256 + n]);
    if (n < 16) {
        __hip_bfloat16 v = __float2bfloat16(n < 8 ? W2[k * 8 + n] : 0.f);
        W2Tp[n * 256 + k] = v;
    }
}

// ---------------- node logits (fp32 vector) + fused z->bf16 cast
__global__ __launch_bounds__(256) void node_kernel(
    const float* __restrict__ z, const float* __restrict__ Wn,
    const float* __restrict__ bn, float* __restrict__ out,
    __hip_bfloat16* __restrict__ zbf) {
    __shared__ float wt[32][132];
    __shared__ float zl[8][128];
    int t = threadIdx.x;
#pragma unroll
    for (int i = 0; i < 16; ++i) {
        int flat = t + 256 * i;
        int k = flat >> 5, ty = flat & 31;
        wt[ty][k] = Wn[flat];
    }
    int node0 = blockIdx.x * 8;
    float4 v = ((const float4*)(z + (size_t)node0 * LATENT))[t];
    ((float4*)zl)[t] = v;
    {
        __hip_bfloat16 o[4];
        o[0] = __float2bfloat16(v.x); o[1] = __float2bfloat16(v.y);
        o[2] = __float2bfloat16(v.z); o[3] = __float2bfloat16(v.w);
        *(uint2*)&zbf[(size_t)node0 * LATENT + t * 4] = *(const uint2*)o;
    }
    __syncthreads();
    int ty = t & 31, ln = t >> 5;
    float acc = bn[ty];
#pragma unroll 16
    for (int k = 0; k < 128; ++k) acc += zl[ln][k] * wt[ty][k];
    out[(size_t)(node0 + ln) * NTYPES + ty] = acc;
}

// ---------------- fused edge MLP, 512-thread blocks, 2(M)x4(N) wave grid, multi-tile pipelined
// ef layout (per buffer): 64 rows x 32 chunks of 16B; chunk swizzle: phys = logical ^ (row & 7)
// NOTE: __launch_bounds__ 2nd arg empirically acts as min BLOCKS/CU here:
//   (512,2) -> VGPR 128 (R5/R7, no spill); (512,4) -> VGPR 64 (R6, breg spilled, FETCH 1.7 GB).
#define W2T_ROW 264

__global__ __launch_bounds__(512, 2) void edge_kernel(
    const __hip_bfloat16* __restrict__ zbf, const int* __restrict__ ei,
    const __hip_bfloat16* __restrict__ W1T, const float* __restrict__ b1,
    const __hip_bfloat16* __restrict__ W2T, const float* __restrict__ b2,
    float* __restrict__ out) {
    __shared__ __align__(16) __hip_bfloat16 ef[2][64 * 256];    // 2 x 32 KB
    __shared__ __align__(16) __hip_bfloat16 w2t[16 * W2T_ROW];  // 8448 B
    __shared__ int idx_lds[2][128];

    int t = threadIdx.x;
    int lane = t & 63, wave = t >> 6;        // 8 waves
    int l16 = lane & 15, quad = lane >> 4;
    int sw = l16 & 7;                        // LDS chunk swizzle for this lane
    int mi = wave >> 2;                      // 0..1  (M half)
    int ni = wave & 3;                       // 0..3  (N quarter)
    int nb = ni * 64;

    bool i64 = ((ei[1] | ei[3] | ei[5] | ei[7] | ei[9] | ei[11] | ei[13] | ei[15]) == 0);

    {   // stage W2T once: 512 threads cover 512 x 16B
        int n = t >> 5, c = t & 31;
        *(uint4*)&w2t[n * W2T_ROW + c * 8] = ((const uint4*)W2T)[t];
    }

    // B panel (N=64 x K=256 per wave) into registers: 32 x bf16x8 = 128 VGPRs
    bf16x8 breg[4][8];
#pragma unroll
    for (int nt = 0; nt < 4; ++nt) {
        const __hip_bfloat16* rowp = W1T + (size_t)(nb + nt * 16 + l16) * 256 + quad * 8;
#pragma unroll
        for (int kt = 0; kt < 8; ++kt) breg[nt][kt] = *(const bf16x8*)(rowp + kt * 32);
    }

    float b1v[4];
#pragma unroll
    for (int nt = 0; nt < 4; ++nt) b1v[nt] = b1[nb + nt * 16 + l16];
    float b2v = (l16 < 8) ? b2[l16] : 0.f;

    int tile = blockIdx.x;
    if (t < 128) idx_lds[0][t] = load_idx(ei, i64, t >> 6, (size_t)tile * 64 + (t & 63));
    __syncthreads();   // idx_lds[0] + w2t visible
    {   // issue DMA gather tile0 -> ef[0]: 8 waves x 4 issues x 64 lanes x 16B = 32 KB
#pragma unroll
        for (int i = 0; i < 4; ++i) {
            int s = (wave * 4 + i) * 64 + lane;
            int m = s >> 5, cp = s & 31;
            int c = cp ^ (m & 7);
            int node = idx_lds[0][(c >> 4) * 64 + m];
            gather16(zbf + (size_t)node * LATENT + (c & 15) * 8, &ef[0][(wave * 4 + i) * 512], lane);
        }
    }
    int v_idx = 0;
    {
        int t1 = tile + GRID_E; if (t1 >= NTILES) t1 = tile;
        if (t < 128) v_idx = load_idx(ei, i64, t >> 6, (size_t)t1 * 64 + (t & 63));
    }

    int cur = 0;
    for (; tile < NTILES; tile += GRID_E) {
        int nxt = cur ^ 1;
        if (t < 128) idx_lds[nxt][t] = v_idx;
        __syncthreads();   // B1: the ONE vmcnt(0) drain point — DMA(cur) had a full tile to land

        {   // issue DMA gather (tile+G) -> ef[nxt]; stays in flight across B2/B3
#pragma unroll
            for (int i = 0; i < 4; ++i) {
                int s = (wave * 4 + i) * 64 + lane;
                int m = s >> 5, cp = s & 31;
                int c = cp ^ (m & 7);
                int node = idx_lds[nxt][(c >> 4) * 64 + m];
                gather16(zbf + (size_t)node * LATENT + (c & 15) * 8, &ef[nxt][(wave * 4 + i) * 512], lane);
            }
        }
        {   // prefetch idx(tile + 2G)
            int t2 = tile + 2 * GRID_E; if (t2 >= NTILES) t2 = tile;
            if (t < 128) v_idx = load_idx(ei, i64, t >> 6, (size_t)t2 * 64 + (t & 63));
        }

        // ---- layer 1 K-loop on ef[cur]; B from registers; wave does M=32 (2 m-tiles), N=64
        const __hip_bfloat16* efc = ef[cur];
        floatx4 acc[2][4];
#pragma unroll
        for (int a = 0; a < 2; ++a)
#pragma unroll
            for (int b = 0; b < 4; ++b) acc[a][b] = floatx4{0.f, 0.f, 0.f, 0.f};

#pragma unroll
        for (int kt = 0; kt < 8; ++kt) {
            bf16x8 afrag[2];
#pragma unroll
            for (int mtl = 0; mtl < 2; ++mtl) {
                int m = (mi * 2 + mtl) * 16 + l16;
                int chunk = m * 32 + ((kt * 4 + quad) ^ sw);
                afrag[mtl] = *(const bf16x8*)&efc[chunk * 8];
            }
#pragma unroll
            for (int mtl = 0; mtl < 2; ++mtl)
#pragma unroll
                for (int nt = 0; nt < 4; ++nt)
                    acc[mtl][nt] = __builtin_amdgcn_mfma_f32_16x16x32_bf16(
                        afrag[mtl], breg[nt][kt], acc[mtl][nt], 0, 0, 0);
        }

        lds_barrier();   // B2: LDS-only — A-reads of ef[cur] done; DMA(nxt) NOT drained

        // ---- ReLU + bias, H -> ef[cur] (swizzled layout)
        __hip_bfloat16* efh = ef[cur];
#pragma unroll
        for (int mtl = 0; mtl < 2; ++mtl)
#pragma unroll
            for (int nt = 0; nt < 4; ++nt)
#pragma unroll
                for (int r = 0; r < 4; ++r) {
                    float v = acc[mtl][nt][r] + b1v[nt];
                    v = v > 0.f ? v : 0.f;
                    int row = (mi * 2 + mtl) * 16 + quad * 4 + r;
                    int col = nb + nt * 16 + l16;
                    int ch = row * 32 + ((col >> 3) ^ (row & 7));
                    efh[ch * 8 + (col & 7)] = __float2bfloat16(v);
                }
        lds_barrier();   // B3: LDS-only — H visible

        // ---- layer 2: waves 0..3 each take one m-tile of 16 edges; N=16 (cols 8..15 zero-padded)
        if (mi == 0) {
            floatx4 acc2 = floatx4{0.f, 0.f, 0.f, 0.f};
#pragma unroll
            for (int kt = 0; kt < 8; ++kt) {
                int m2 = ni * 16 + l16;
                int chunk = m2 * 32 + ((kt * 4 + quad) ^ sw);
                bf16x8 a2 = *(const bf16x8*)&efc[chunk * 8];
                bf16x8 b2f = *(const bf16x8*)&w2t[l16 * W2T_ROW + (kt * 4 + quad) * 8];
                acc2 = __builtin_amdgcn_mfma_f32_16x16x32_bf16(a2, b2f, acc2, 0, 0, 0);
            }
            if (l16 < 8) {
                size_t e0 = (size_t)tile * 64;
#pragma unroll
                for (int r = 0; r < 4; ++r) {
                    size_t erow = e0 + ni * 16 + quad * 4 + r;
                    out[erow * 8 + l16] = acc2[r] + b2v;
                }
            }
        }
        cur ^= 1;
    }
}

extern "C" void kernel_launch(void* const* d_in, const int* in_sizes, int n_in,
                              void* d_out, int out_size, void* d_ws, size_t ws_size,
                              hipStream_t stream) {
    const float* z  = (const float*)d_in[0];
    const int* ei   = (const int*)d_in[1];
    const float* Wn = (const float*)d_in[2];
    const float* bn = (const float*)d_in[3];
    const float* W1 = (const float*)d_in[4];
    const float* b1 = (const float*)d_in[5];
    const float* W2 = (const float*)d_in[6];
    const float* b2 = (const float*)d_in[7];
    float* out = (float*)d_out;

    __hip_bfloat16* zbf  = (__hip_bfloat16*)d_ws;            // 6,400,000 bf16
    __hip_bfloat16* W1T  = zbf + (size_t)NNODES * LATENT;    // 65,536 bf16
    __hip_bfloat16* W2Tp = W1T + 256 * 256;                  // 4,096 bf16

    hipLaunchKernelGGL(transpose_kernel, dim3(256), dim3(256), 0, stream, W1, W2, W1T, W2Tp);
    hipLaunchKernelGGL(node_kernel, dim3(NNODES / 8), dim3(256), 0, stream, z, Wn, bn, out, zbf);
    hipLaunchKernelGGL(edge_kernel, dim3(GRID_E), dim3(512), 0, stream,
                       zbf, ei, W1T, b1, W2Tp, b2, out + (size_t)NNODES * NTYPES);
}

// Round 9
// 214.920 us; speedup vs baseline: 2.9173x; 1.1709x over previous
//
#include <hip/hip_runtime.h>
#include <hip/hip_bf16.h>
#include <stdint.h>

#define NNODES 50000
#define NEDGES 800000
#define LATENT 128
#define NTYPES 32
#define NTILES 25000   // NEDGES / 32 (32-edge tiles)
#define GRID_E 512     // 2 blocks/CU target

typedef __bf16 bf16x8 __attribute__((ext_vector_type(8)));
typedef float floatx4 __attribute__((ext_vector_type(4)));
typedef unsigned int u32;

#if defined(__has_builtin)
#if __has_builtin(__builtin_amdgcn_global_load_lds)
#define HAS_GLD_LDS 1
#endif
#endif

// LDS-only barrier: waits lgkmcnt(0) but leaves vmcnt (async DMA) in flight.
__device__ __forceinline__ void lds_barrier() {
    asm volatile("s_waitcnt lgkmcnt(0)\n\ts_barrier" ::: "memory");
}

// async 16B/lane gather into LDS. lbase must be wave-uniform; HW deposits at lbase + lane*16.
__device__ __forceinline__ void gather16(const __hip_bfloat16* g, __hip_bfloat16* lbase, int lane) {
#ifdef HAS_GLD_LDS
    __builtin_amdgcn_global_load_lds(
        (const __attribute__((address_space(1))) u32*)(uintptr_t)g,
        (__attribute__((address_space(3))) u32*)(u32)(uintptr_t)lbase,
        16, 0, 0);
#else
    *(uint4*)(lbase + lane * 8) = *(const uint4*)g;
#endif
}

__device__ __forceinline__ int load_idx(const int* ei, bool i64, int half, size_t e) {
    size_t pos = (size_t)half * NEDGES + e;
    return i64 ? ei[2 * pos] : ei[pos];
}

// ---------------- transpose+cast W1 -> W1T[256][256] bf16, W2 -> W2Tp[16][256] bf16 (rows 8..15 zero)
__global__ __launch_bounds__(256) void transpose_kernel(
    const float* __restrict__ W1, const float* __restrict__ W2,
    __hip_bfloat16* __restrict__ W1T, __hip_bfloat16* __restrict__ W2Tp) {
    int n = blockIdx.x;   // 0..255
    int k = threadIdx.x;  // 0..255
    W1T[n * 256 + k] = __float2bfloat16(W1[k * 256 + n]);
    if (n < 16) {
        __hip_bfloat16 v = __float2bfloat16(n < 8 ? W2[k * 8 + n] : 0.f);
        W2Tp[n * 256 + k] = v;
    }
}

// ---------------- node logits (fp32 vector) + fused z->bf16 cast
__global__ __launch_bounds__(256) void node_kernel(
    const float* __restrict__ z, const float* __restrict__ Wn,
    const float* __restrict__ bn, float* __restrict__ out,
    __hip_bfloat16* __restrict__ zbf) {
    __shared__ float wt[32][129];  // stride 129: bank = (ty+k)%32, conflict-free (132 was 4-way)
    __shared__ float zl[8][128];
    int t = threadIdx.x;
#pragma unroll
    for (int i = 0; i < 16; ++i) {
        int flat = t + 256 * i;
        int k = flat >> 5, ty = flat & 31;
        wt[ty][k] = Wn[flat];
    }
    int node0 = blockIdx.x * 8;
    float4 v = ((const float4*)(z + (size_t)node0 * LATENT))[t];
    ((float4*)zl)[t] = v;
    {
        __hip_bfloat16 o[4];
        o[0] = __float2bfloat16(v.x); o[1] = __float2bfloat16(v.y);
        o[2] = __float2bfloat16(v.z); o[3] = __float2bfloat16(v.w);
        *(uint2*)&zbf[(size_t)node0 * LATENT + t * 4] = *(const uint2*)o;
    }
    __syncthreads();
    int ty = t & 31, ln = t >> 5;
    float acc = bn[ty];
#pragma unroll 16
    for (int k = 0; k < 128; ++k) acc += zl[ln][k] * wt[ty][k];
    out[(size_t)(node0 + ln) * NTYPES + ty] = acc;
}

// ---------------- fused edge MLP: 256-thread blocks, 32-edge tiles, 2 blocks/CU
// Layer-1 MFMA operands SWAPPED vs R2-R8: A = W1T (m=hidden), B = ef (n=edge).
// C-layout: row(quad*4+r) = hidden, col(l16) = edge -> epilogue packs 4 consecutive
// hidden values into one ds_write_b64 (was 32 scalar b16 writes with 4-way conflicts).
// ef layout: 32 rows(edges) x 32 chunks of 16B; phys chunk = logical ^ (edge & 7).
// VGPR calibration: cap = 2048 / (blocks * waves_per_block); (256,2) -> 256 cap, need ~210.
#define W2T_ROW 264

__global__ __launch_bounds__(256, 2) void edge_kernel(
    const __hip_bfloat16* __restrict__ zbf, const int* __restrict__ ei,
    const __hip_bfloat16* __restrict__ W1T, const float* __restrict__ b1,
    const __hip_bfloat16* __restrict__ W2T, const float* __restrict__ b2,
    float* __restrict__ out) {
    __shared__ __align__(16) __hip_bfloat16 ef[2][32 * 256];    // 2 x 16 KB
    __shared__ __align__(16) __hip_bfloat16 w2t[16 * W2T_ROW];  // 8448 B
    __shared__ int idx_lds[2][64];

    int t = threadIdx.x;                     // 0..255
    int lane = t & 63, wave = t >> 6;        // 4 waves
    int l16 = lane & 15, quad = lane >> 4;
    int sw = l16 & 7;                        // edge&7 for this lane's fragment rows
    int nb = wave * 64;                      // this wave's hidden slice [nb, nb+64)

    bool i64 = ((ei[1] | ei[3] | ei[5] | ei[7] | ei[9] | ei[11] | ei[13] | ei[15]) == 0);

    {   // stage W2T once: 512 chunks of 16B
        const uint4* src = (const uint4*)W2T;
#pragma unroll
        for (int i = 0; i < 2; ++i) {
            int p = t + 256 * i;
            int n = p >> 5, c = p & 31;
            *(uint4*)&w2t[n * W2T_ROW + c * 8] = src[p];
        }
    }

    // A panel: W1T rows for this wave's 64-hidden slice, K=256: 32 x bf16x8 = 128 VGPRs
    bf16x8 breg[4][8];
#pragma unroll
    for (int nt = 0; nt < 4; ++nt) {
        const __hip_bfloat16* rowp = W1T + (size_t)(nb + nt * 16 + l16) * 256 + quad * 8;
#pragma unroll
        for (int kt = 0; kt < 8; ++kt) breg[nt][kt] = *(const bf16x8*)(rowp + kt * 32);
    }

    // bias: b1 over hidden = nb + nt*16 + quad*4 + r  (4 aligned float4 loads)
    floatx4 b1v[4];
#pragma unroll
    for (int nt = 0; nt < 4; ++nt)
        b1v[nt] = *(const floatx4*)&b1[nb + nt * 16 + quad * 4];
    float b2v = (l16 < 8) ? b2[l16] : 0.f;

    int tile = blockIdx.x;
    if (t < 64) idx_lds[0][t] = load_idx(ei, i64, t >> 5, (size_t)tile * 32 + (t & 31));
    __syncthreads();   // idx_lds[0] + w2t visible
    {   // issue DMA gather tile0 -> ef[0]: 16 instr x 64 lanes x 16B = 16 KB
#pragma unroll
        for (int i = 0; i < 4; ++i) {
            int ii = wave * 4 + i;           // 0..15
            int s = ii * 64 + lane;
            int e = s >> 5, cp = s & 31;
            int c = cp ^ (e & 7);
            int node = idx_lds[0][(c >> 4) * 32 + e];
            gather16(zbf + (size_t)node * LATENT + (c & 15) * 8, &ef[0][ii * 512], lane);
        }
    }
    int v_idx = 0;
    {
        int t1 = tile + GRID_E; if (t1 >= NTILES) t1 = tile;
        if (t < 64) v_idx = load_idx(ei, i64, t >> 5, (size_t)t1 * 32 + (t & 31));
    }

    int cur = 0;
    for (; tile < NTILES; tile += GRID_E) {
        int nxt = cur ^ 1;
        if (t < 64) idx_lds[nxt][t] = v_idx;
        __syncthreads();   // B1: the one vmcnt(0) drain — DMA(cur) had a full tile to land

        {   // issue DMA gather (tile+G) -> ef[nxt]; stays in flight across B2/B3
#pragma unroll
            for (int i = 0; i < 4; ++i) {
                int ii = wave * 4 + i;
                int s = ii * 64 + lane;
                int e = s >> 5, cp = s & 31;
                int c = cp ^ (e & 7);
                int node = idx_lds[nxt][(c >> 4) * 32 + e];
                gather16(zbf + (size_t)node * LATENT + (c & 15) * 8, &ef[nxt][ii * 512], lane);
            }
        }
        {   // prefetch idx(tile + 2G)
            int t2 = tile + 2 * GRID_E; if (t2 >= NTILES) t2 = tile;
            if (t < 64) v_idx = load_idx(ei, i64, t >> 5, (size_t)t2 * 32 + (t & 31));
        }

        // ---- layer 1: A = breg (hidden), B = ef (edges); wave: M=64 hidden x N=32 edges
        const __hip_bfloat16* efc = ef[cur];
        floatx4 acc[4][2];
#pragma unroll
        for (int a = 0; a < 4; ++a)
#pragma unroll
            for (int b = 0; b < 2; ++b) acc[a][b] = floatx4{0.f, 0.f, 0.f, 0.f};

#pragma unroll
        for (int kt = 0; kt < 8; ++kt) {
            bf16x8 bfrag[2];
#pragma unroll
            for (int et = 0; et < 2; ++et) {
                int e = et * 16 + l16;
                int chunk = e * 32 + ((kt * 4 + quad) ^ sw);
                bfrag[et] = *(const bf16x8*)&efc[chunk * 8];
            }
#pragma unroll
            for (int nt = 0; nt < 4; ++nt)
#pragma unroll
                for (int et = 0; et < 2; ++et)
                    acc[nt][et] = __builtin_amdgcn_mfma_f32_16x16x32_bf16(
                        breg[nt][kt], bfrag[et], acc[nt][et], 0, 0, 0);
        }

        lds_barrier();   // B2: LDS-only — B-reads of ef[cur] done; DMA(nxt) not drained

        // ---- ReLU + bias, H -> ef[cur]: lane packs 4 consecutive hidden -> ds_write_b64
        __hip_bfloat16* efh = ef[cur];
#pragma unroll
        for (int nt = 0; nt < 4; ++nt)
#pragma unroll
            for (int et = 0; et < 2; ++et) {
                __hip_bfloat16 pk[4];
#pragma unroll
                for (int r = 0; r < 4; ++r) {
                    float v = acc[nt][et][r] + b1v[nt][r];
                    pk[r] = __float2bfloat16(v > 0.f ? v : 0.f);
                }
                int e = et * 16 + l16;
                int hb = nb + nt * 16 + quad * 4;        // aligned 4-elem group
                int phys = (hb >> 3) ^ (e & 7);
                *(uint2*)&efh[e * 256 + phys * 8 + (hb & 7)] = *(const uint2*)pk;
            }
        lds_barrier();   // B3: LDS-only — H visible

        // ---- layer 2: waves 0..1 each take 16 edges; A = H rows, B = w2t; N=16 (8 padded)
        if (wave < 2) {
            floatx4 acc2 = floatx4{0.f, 0.f, 0.f, 0.f};
#pragma unroll
            for (int kt = 0; kt < 8; ++kt) {
                int e = wave * 16 + l16;
                int chunk = e * 32 + ((kt * 4 + quad) ^ sw);
                bf16x8 a2 = *(const bf16x8*)&efc[chunk * 8];
                bf16x8 b2f = *(const bf16x8*)&w2t[l16 * W2T_ROW + (kt * 4 + quad) * 8];
                acc2 = __builtin_amdgcn_mfma_f32_16x16x32_bf16(a2, b2f, acc2, 0, 0, 0);
            }
            if (l16 < 8) {
                size_t e0 = (size_t)tile * 32;
#pragma unroll
                for (int r = 0; r < 4; ++r) {
                    size_t erow = e0 + wave * 16 + quad * 4 + r;
                    out[erow * 8 + l16] = acc2[r] + b2v;
                }
            }
        }
        cur ^= 1;
    }
}

extern "C" void kernel_launch(void* const* d_in, const int* in_sizes, int n_in,
                              void* d_out, int out_size, void* d_ws, size_t ws_size,
                              hipStream_t stream) {
    const float* z  = (const float*)d_in[0];
    const int* ei   = (const int*)d_in[1];
    const float* Wn = (const float*)d_in[2];
    const float* bn = (const float*)d_in[3];
    const float* W1 = (const float*)d_in[4];
    const float* b1 = (const float*)d_in[5];
    const float* W2 = (const float*)d_in[6];
    const float* b2 = (const float*)d_in[7];
    float* out = (float*)d_out;

    __hip_bfloat16* zbf  = (__hip_bfloat16*)d_ws;            // 6,400,000 bf16
    __hip_bfloat16* W1T  = zbf + (size_t)NNODES * LATENT;    // 65,536 bf16
    __hip_bfloat16* W2Tp = W1T + 256 * 256;                  // 4,096 bf16

    hipLaunchKernelGGL(transpose_kernel, dim3(256), dim3(256), 0, stream, W1, W2, W1T, W2Tp);
    hipLaunchKernelGGL(node_kernel, dim3(NNODES / 8), dim3(256), 0, stream, z, Wn, bn, out, zbf);
    hipLaunchKernelGGL(edge_kernel, dim3(GRID_E), dim3(256), 0, stream,
                       zbf, ei, W1T, b1, W2Tp, b2, out + (size_t)NNODES * NTYPES);
}